// Round 1
// baseline (854.828 us; speedup 1.0000x reference)
//
#include <hip/hip_runtime.h>
#include <math.h>

#define NEG_SLOPE 0.2f

__device__ __forceinline__ float lrelu(float x) { return x > 0.f ? x : NEG_SLOPE * x; }

// Works for mixed signs given init to a very negative float:
// positives race via signed-int max, negatives via unsigned-int min;
// cross cases resolve correctly because positive floats compare above
// negative floats in both int spaces used.
__device__ __forceinline__ void atomicMaxFloat(float* addr, float val) {
    if (val >= 0.f) atomicMax((int*)addr, __float_as_int(val));
    else            atomicMin((unsigned int*)addr, __float_as_uint(val));
}

// ---------------------------------------------------------------------------
// K1: h[n, ho] = sum_i x[n,i] * W[i, ho]    (N x 128) @ (128 x 128)
// Block: 256 threads, 32 rows x 128 cols per block.
// W (64KB) + x tile (stride 129, 16.1KB) in LDS.
// ---------------------------------------------------------------------------
__global__ __launch_bounds__(256) void k_gemm(const float* __restrict__ x,
                                              const float* __restrict__ w,
                                              float* __restrict__ hout, int N) {
    __shared__ float Ws[128 * 128];
    __shared__ float Xs[32 * 129];
    const int t = threadIdx.x;
    const int row0 = blockIdx.x * 32;

    // stage W: 16384 floats = 4096 float4, coalesced
    {
        const float4* w4 = (const float4*)w;
        float4* s4 = (float4*)Ws;
        #pragma unroll
        for (int i = 0; i < 16; ++i) s4[t + 256 * i] = w4[t + 256 * i];
    }
    // stage x rows (pad stride 129 to kill bank conflicts on the k-scan)
    {
        #pragma unroll
        for (int i = 0; i < 4; ++i) {
            int idx = t + 256 * i;            // 0..1023 float4 slots
            int r = idx >> 5, c4 = (idx & 31) * 4;
            float4 v = make_float4(0.f, 0.f, 0.f, 0.f);
            if (row0 + r < N) v = *(const float4*)(x + (size_t)(row0 + r) * 128 + c4);
            float* xp = &Xs[r * 129 + c4];
            xp[0] = v.x; xp[1] = v.y; xp[2] = v.z; xp[3] = v.w;
        }
    }
    __syncthreads();

    const int r = t & 31;          // row within tile
    const int c0 = (t >> 5) * 16;  // 8 col-groups of 16
    float acc[16] = {};
    for (int k = 0; k < 128; ++k) {
        float xv = Xs[r * 129 + k];
        #pragma unroll
        for (int j = 0; j < 4; ++j) {
            float4 b = *(const float4*)&Ws[k * 128 + c0 + 4 * j];
            acc[4 * j + 0] += xv * b.x;
            acc[4 * j + 1] += xv * b.y;
            acc[4 * j + 2] += xv * b.z;
            acc[4 * j + 3] += xv * b.w;
        }
    }
    if (row0 + r < N) {
        float* op = hout + (size_t)(row0 + r) * 128 + c0;
        #pragma unroll
        for (int j = 0; j < 4; ++j) {
            float4 v = make_float4(acc[4 * j], acc[4 * j + 1], acc[4 * j + 2], acc[4 * j + 3]);
            *(float4*)(op + 4 * j) = v;
        }
    }
}

// ---------------------------------------------------------------------------
// K2: init out = 0, smax = -1e30, denom = 0
// ---------------------------------------------------------------------------
__global__ __launch_bounds__(256) void k_init(float* __restrict__ out,
                                              float* __restrict__ smax,
                                              float* __restrict__ denom, int N) {
    int tid = blockIdx.x * blockDim.x + threadIdx.x;
    if (tid < N * 128) out[tid] = 0.f;
    if (tid < N * 4) { smax[tid] = -1e30f; denom[tid] = 0.f; }
}

// ---------------------------------------------------------------------------
// K3: per-node attention dots: adot_i[n,h] = <h[n,h,:], a_i[h,:]>, same for j
// att layout: (H, 2*O) -> a_i = att[h, :32], a_j = att[h, 32:]
// ---------------------------------------------------------------------------
__global__ __launch_bounds__(256) void k_adot(const float* __restrict__ h,
                                              const float* __restrict__ att,
                                              float* __restrict__ adi,
                                              float* __restrict__ adj, int N) {
    int tid = blockIdx.x * blockDim.x + threadIdx.x;
    if (tid >= N * 4) return;
    int n = tid >> 2, head = tid & 3;
    const float* hp = h + (size_t)n * 128 + head * 32;
    const float* aw = att + head * 64;
    float si = 0.f, sj = 0.f;
    #pragma unroll 8
    for (int o = 0; o < 32; ++o) {
        float hv = hp[o];
        si += hv * aw[o];
        sj += hv * aw[32 + o];
    }
    adi[tid] = si;
    adj[tid] = sj;
}

// ---------------------------------------------------------------------------
// K4: segment max of adot_j over dst (leaky_relu commutes with max since
// adot_i[dst] is constant per segment and lrelu is monotone)
// ---------------------------------------------------------------------------
__global__ __launch_bounds__(256) void k_smax(const int* __restrict__ ei,
                                              const float* __restrict__ adj,
                                              float* __restrict__ smax, int E) {
    int tid = blockIdx.x * blockDim.x + threadIdx.x;
    if (tid >= E * 4) return;
    int e = tid >> 2, head = tid & 3;
    int src = ei[e], dst = ei[E + e];
    atomicMaxFloat(&smax[dst * 4 + head], adj[src * 4 + head]);
}

// ---------------------------------------------------------------------------
// K5: main edge pass. One wave (64 lanes) per edge.
// lane owns output elems 2*lane, 2*lane+1 (both in head lane>>4).
// ex = exp(lrelu(ai+aj) - lrelu(ai+smax))  (max-edge is bit-identical -> <=1)
// out[dst] += h[src]*ex (numerator), denom[dst,h] += ex; divide later.
// ---------------------------------------------------------------------------
__global__ __launch_bounds__(256) void k_edge_acc(const int* __restrict__ ei,
                                                  const float* __restrict__ h,
                                                  const float* __restrict__ adi,
                                                  const float* __restrict__ adj,
                                                  const float* __restrict__ smax,
                                                  float* __restrict__ denom,
                                                  float* __restrict__ out, int E) {
    int tid = blockIdx.x * blockDim.x + threadIdx.x;
    int e = tid >> 6;
    if (e >= E) return;
    int lane = tid & 63;
    int src = ei[e], dst = ei[E + e];
    int head = lane >> 4;

    float ai = adi[dst * 4 + head];
    float aj = adj[src * 4 + head];
    float sm = smax[dst * 4 + head];
    float ex = __expf(lrelu(ai + aj) - lrelu(ai + sm));

    if ((lane & 15) == 0) atomicAdd(&denom[dst * 4 + head], ex);

    float2 hv = ((const float2*)h)[(size_t)src * 64 + lane];
    atomicAdd(&out[(size_t)dst * 128 + 2 * lane + 0], hv.x * ex);
    atomicAdd(&out[(size_t)dst * 128 + 2 * lane + 1], hv.y * ex);
}

// ---------------------------------------------------------------------------
// K6: out = out / (denom + 1e-16) + bias
// ---------------------------------------------------------------------------
__global__ __launch_bounds__(256) void k_final(float* __restrict__ out,
                                               const float* __restrict__ denom,
                                               const float* __restrict__ bias, int N) {
    int tid = blockIdx.x * blockDim.x + threadIdx.x;
    if (tid >= N * 128) return;
    int n = tid >> 7, ho = tid & 127, head = ho >> 5;
    out[tid] = out[tid] / (denom[n * 4 + head] + 1e-16f) + bias[ho];
}

extern "C" void kernel_launch(void* const* d_in, const int* in_sizes, int n_in,
                              void* d_out, int out_size, void* d_ws, size_t ws_size,
                              hipStream_t stream) {
    const float* x    = (const float*)d_in[0];
    const int*   ei   = (const int*)d_in[1];
    const float* w    = (const float*)d_in[2];
    const float* att  = (const float*)d_in[3];
    const float* bias = (const float*)d_in[4];

    const int N = in_sizes[0] / 128;   // 50000
    const int E = in_sizes[1] / 2;     // 800000

    float* out = (float*)d_out;
    float* ws  = (float*)d_ws;
    float* h     = ws;                         // N*128
    float* adi   = h + (size_t)N * 128;        // N*4
    float* adj   = adi + (size_t)N * 4;        // N*4
    float* smax  = adj + (size_t)N * 4;        // N*4
    float* denom = smax + (size_t)N * 4;       // N*4

    k_gemm<<<(N + 31) / 32, 256, 0, stream>>>(x, w, h, N);
    k_init<<<(N * 128 + 255) / 256, 256, 0, stream>>>(out, smax, denom, N);
    k_adot<<<(N * 4 + 255) / 256, 256, 0, stream>>>(h, att, adi, adj, N);
    k_smax<<<(E * 4 + 255) / 256, 256, 0, stream>>>(ei, adj, smax, E);
    {
        long long total = (long long)E * 64;
        int blocks = (int)((total + 255) / 256);
        k_edge_acc<<<blocks, 256, 0, stream>>>(ei, h, adi, adj, smax, denom, out, E);
    }
    k_final<<<(N * 128 + 255) / 256, 256, 0, stream>>>(out, denom, bias, N);
}

// Round 2
// 378.239 us; speedup vs baseline: 2.2600x; 2.2600x over previous
//
#include <hip/hip_runtime.h>
#include <math.h>

#define NEG_SLOPE 0.2f

__device__ __forceinline__ float lrelu(float x) { return x > 0.f ? x : NEG_SLOPE * x; }

// ---------------------------------------------------------------------------
// K1: h[n, ho] = sum_i x[n,i] * W[i, ho]    (N x 128) @ (128 x 128)
// ---------------------------------------------------------------------------
__global__ __launch_bounds__(256) void k_gemm(const float* __restrict__ x,
                                              const float* __restrict__ w,
                                              float* __restrict__ hout, int N) {
    __shared__ float Ws[128 * 128];
    __shared__ float Xs[32 * 129];
    const int t = threadIdx.x;
    const int row0 = blockIdx.x * 32;

    {
        const float4* w4 = (const float4*)w;
        float4* s4 = (float4*)Ws;
        #pragma unroll
        for (int i = 0; i < 16; ++i) s4[t + 256 * i] = w4[t + 256 * i];
    }
    {
        #pragma unroll
        for (int i = 0; i < 4; ++i) {
            int idx = t + 256 * i;
            int r = idx >> 5, c4 = (idx & 31) * 4;
            float4 v = make_float4(0.f, 0.f, 0.f, 0.f);
            if (row0 + r < N) v = *(const float4*)(x + (size_t)(row0 + r) * 128 + c4);
            float* xp = &Xs[r * 129 + c4];
            xp[0] = v.x; xp[1] = v.y; xp[2] = v.z; xp[3] = v.w;
        }
    }
    __syncthreads();

    const int r = t & 31;
    const int c0 = (t >> 5) * 16;
    float acc[16] = {};
    for (int k = 0; k < 128; ++k) {
        float xv = Xs[r * 129 + k];
        #pragma unroll
        for (int j = 0; j < 4; ++j) {
            float4 b = *(const float4*)&Ws[k * 128 + c0 + 4 * j];
            acc[4 * j + 0] += xv * b.x;
            acc[4 * j + 1] += xv * b.y;
            acc[4 * j + 2] += xv * b.z;
            acc[4 * j + 3] += xv * b.w;
        }
    }
    if (row0 + r < N) {
        float* op = hout + (size_t)(row0 + r) * 128 + c0;
        #pragma unroll
        for (int j = 0; j < 4; ++j) {
            float4 v = make_float4(acc[4 * j], acc[4 * j + 1], acc[4 * j + 2], acc[4 * j + 3]);
            *(float4*)(op + 4 * j) = v;
        }
    }
}

// ---------------------------------------------------------------------------
// K2: per-node attention dots adi/adj
// ---------------------------------------------------------------------------
__global__ __launch_bounds__(256) void k_adot(const float* __restrict__ h,
                                              const float* __restrict__ att,
                                              float* __restrict__ adi,
                                              float* __restrict__ adj, int N) {
    int tid = blockIdx.x * blockDim.x + threadIdx.x;
    if (tid >= N * 4) return;
    int n = tid >> 2, head = tid & 3;
    const float* hp = h + (size_t)n * 128 + head * 32;
    const float* aw = att + head * 64;
    float si = 0.f, sj = 0.f;
    #pragma unroll 8
    for (int o = 0; o < 32; ++o) {
        float hv = hp[o];
        si += hv * aw[o];
        sj += hv * aw[32 + o];
    }
    adi[tid] = si;
    adj[tid] = sj;
}

// ---------------------------------------------------------------------------
// CSR build: zero counts -> histogram -> single-block scan -> scatter
// ---------------------------------------------------------------------------
__global__ __launch_bounds__(256) void k_zero(int* __restrict__ cnt, int N) {
    int tid = blockIdx.x * blockDim.x + threadIdx.x;
    if (tid < N) cnt[tid] = 0;
}

__global__ __launch_bounds__(256) void k_hist(const int* __restrict__ ei,
                                              int* __restrict__ cnt, int E) {
    int e = blockIdx.x * blockDim.x + threadIdx.x;
    if (e >= E) return;
    atomicAdd(&cnt[ei[E + e]], 1);
}

// single-block exclusive scan of cnt[0..N) -> rowoff[0..N], cursor copy
__global__ __launch_bounds__(1024) void k_scan(const int* __restrict__ cnt,
                                               int* __restrict__ rowoff,
                                               int* __restrict__ cursor, int N) {
    __shared__ int s[1024];
    const int t = threadIdx.x;
    const int chunk = (N + 1023) >> 10;
    const int b = t * chunk;
    const int e = min(b + chunk, N);
    int sum = 0;
    for (int i = b; i < e; ++i) sum += cnt[i];
    s[t] = sum;
    __syncthreads();
    for (int off = 1; off < 1024; off <<= 1) {
        int v = (t >= off) ? s[t - off] : 0;
        __syncthreads();
        s[t] += v;
        __syncthreads();
    }
    int run = (t == 0) ? 0 : s[t - 1];
    for (int i = b; i < e; ++i) {
        rowoff[i] = run; cursor[i] = run;
        run += cnt[i];
    }
    if (b < N && e == N) rowoff[N] = run;
}

__global__ __launch_bounds__(256) void k_scatter(const int* __restrict__ ei,
                                                 int* __restrict__ cursor,
                                                 int* __restrict__ csr_src, int E) {
    int e = blockIdx.x * blockDim.x + threadIdx.x;
    if (e >= E) return;
    int dst = ei[E + e];
    int pos = atomicAdd(&cursor[dst], 1);
    csr_src[pos] = ei[e];
}

// ---------------------------------------------------------------------------
// K3: one wave per node. Pass A: per-head max of adot_j over neighbors
// (shuffle reduce). Pass B: register-accumulated weighted sum + denom.
// Writes final out (with bias) once. Zero atomics.
// ---------------------------------------------------------------------------
__global__ __launch_bounds__(256) void k_node(const int* __restrict__ rowoff,
                                              const int* __restrict__ csr_src,
                                              const float* __restrict__ h,
                                              const float* __restrict__ adi,
                                              const float* __restrict__ adj,
                                              const float* __restrict__ bias,
                                              float* __restrict__ out, int N) {
    int node = (blockIdx.x * blockDim.x + threadIdx.x) >> 6;
    if (node >= N) return;
    const int lane = threadIdx.x & 63;
    const int head = lane >> 4;

    const int beg = rowoff[node];
    const int end = rowoff[node + 1];

    // ---- pass A: max over neighbors of adj[src, h] for h = lane&3 ----
    float m = -1e30f;
    for (int i = beg + (lane >> 2); i < end; i += 16)
        m = fmaxf(m, adj[csr_src[i] * 4 + (lane & 3)]);
    #pragma unroll
    for (int mask = 4; mask <= 32; mask <<= 1)
        m = fmaxf(m, __shfl_xor(m, mask));
    // lane l now holds max for head (l&3); fetch max for head (lane>>4)
    float sm = __shfl(m, head);

    float ai = adi[node * 4 + head];
    float smax_l = lrelu(ai + sm);

    // ---- pass B: accumulate numerator (2 floats/lane) + denom ----
    float acc0 = 0.f, acc1 = 0.f, dsum = 0.f;
    for (int i = beg; i < end; ++i) {
        int src = csr_src[i];
        float aj = adj[src * 4 + head];
        float ex = __expf(lrelu(ai + aj) - smax_l);
        dsum += ex;
        float2 hv = ((const float2*)h)[(size_t)src * 64 + lane];
        acc0 += hv.x * ex;
        acc1 += hv.y * ex;
    }
    // all 16 lanes of a head group computed identical dsum
    float inv = 1.f / (dsum + 1e-16f);
    float2 bv = ((const float2*)bias)[lane];
    float2 ov = make_float2(acc0 * inv + bv.x, acc1 * inv + bv.y);
    ((float2*)out)[(size_t)node * 64 + lane] = ov;
}

extern "C" void kernel_launch(void* const* d_in, const int* in_sizes, int n_in,
                              void* d_out, int out_size, void* d_ws, size_t ws_size,
                              hipStream_t stream) {
    const float* x    = (const float*)d_in[0];
    const int*   ei   = (const int*)d_in[1];
    const float* w    = (const float*)d_in[2];
    const float* att  = (const float*)d_in[3];
    const float* bias = (const float*)d_in[4];

    const int N = in_sizes[0] / 128;   // 50000
    const int E = in_sizes[1] / 2;     // 800000

    float* out = (float*)d_out;
    char*  wsb = (char*)d_ws;

    float* h   = (float*)wsb;                                  // N*128 f
    float* adi = h + (size_t)N * 128;                          // N*4 f
    float* adj = adi + (size_t)N * 4;                          // N*4 f
    int* cnt     = (int*)(adj + (size_t)N * 4);                // N
    int* rowoff  = cnt + N;                                    // N+1
    int* cursor  = rowoff + (N + 1);                           // N
    int* csr_src = cursor + N;                                 // E

    k_gemm<<<(N + 31) / 32, 256, 0, stream>>>(x, w, h, N);
    k_adot<<<(N * 4 + 255) / 256, 256, 0, stream>>>(h, att, adi, adj, N);

    k_zero<<<(N + 255) / 256, 256, 0, stream>>>(cnt, N);
    k_hist<<<(E + 255) / 256, 256, 0, stream>>>(ei, cnt, E);
    k_scan<<<1, 1024, 0, stream>>>(cnt, rowoff, cursor, N);
    k_scatter<<<(E + 255) / 256, 256, 0, stream>>>(ei, cursor, csr_src, E);

    {
        long long total = (long long)N * 64;
        int blocks = (int)((total + 255) / 256);
        k_node<<<blocks, 256, 0, stream>>>(rowoff, csr_src, h, adi, adj, bias, out, N);
    }
}

// Round 3
// 276.523 us; speedup vs baseline: 3.0913x; 1.3678x over previous
//
#include <hip/hip_runtime.h>
#include <math.h>

#define NEG_SLOPE 0.2f

__device__ __forceinline__ float lrelu(float x) { return x > 0.f ? x : NEG_SLOPE * x; }

// ---------------------------------------------------------------------------
// K1: h[n, ho] = sum_i x[n,i] * W[i, ho]    (N x 128) @ (128 x 128)
// Epilogue fused: adi/adj per-node attention dots (saves a 25.6MB pass).
// ---------------------------------------------------------------------------
__global__ __launch_bounds__(256) void k_gemm(const float* __restrict__ x,
                                              const float* __restrict__ w,
                                              const float* __restrict__ att,
                                              float* __restrict__ hout,
                                              float* __restrict__ adi,
                                              float* __restrict__ adj, int N) {
    __shared__ float Ws[128 * 128];
    __shared__ float Xs[32 * 129];
    const int t = threadIdx.x;
    const int row0 = blockIdx.x * 32;

    {
        const float4* w4 = (const float4*)w;
        float4* s4 = (float4*)Ws;
        #pragma unroll
        for (int i = 0; i < 16; ++i) s4[t + 256 * i] = w4[t + 256 * i];
    }
    {
        #pragma unroll
        for (int i = 0; i < 4; ++i) {
            int idx = t + 256 * i;
            int r = idx >> 5, c4 = (idx & 31) * 4;
            float4 v = make_float4(0.f, 0.f, 0.f, 0.f);
            if (row0 + r < N) v = *(const float4*)(x + (size_t)(row0 + r) * 128 + c4);
            float* xp = &Xs[r * 129 + c4];
            xp[0] = v.x; xp[1] = v.y; xp[2] = v.z; xp[3] = v.w;
        }
    }
    __syncthreads();

    const int r = t & 31;          // row in tile
    const int c0 = (t >> 5) * 16;  // 16-col group
    float acc[16] = {};
    for (int k = 0; k < 128; ++k) {
        float xv = Xs[r * 129 + k];
        #pragma unroll
        for (int j = 0; j < 4; ++j) {
            float4 b = *(const float4*)&Ws[k * 128 + c0 + 4 * j];
            acc[4 * j + 0] += xv * b.x;
            acc[4 * j + 1] += xv * b.y;
            acc[4 * j + 2] += xv * b.z;
            acc[4 * j + 3] += xv * b.w;
        }
    }
    const int row = row0 + r;
    if (row < N) {
        float* op = hout + (size_t)row * 128 + c0;
        #pragma unroll
        for (int j = 0; j < 4; ++j) {
            float4 v = make_float4(acc[4 * j], acc[4 * j + 1], acc[4 * j + 2], acc[4 * j + 3]);
            *(float4*)(op + 4 * j) = v;
        }
    }

    // ---- fused attention-dot epilogue ----
    const int hd = c0 >> 5;            // head of this col group
    const int half = (c0 >> 4) & 1;    // which 16-col half of the head
    float si = 0.f, sj = 0.f;
    #pragma unroll
    for (int j = 0; j < 16; ++j) {
        float ai_w = att[hd * 64 + (c0 & 31) + j];
        float aj_w = att[hd * 64 + 32 + (c0 & 31) + j];
        si += acc[j] * ai_w;
        sj += acc[j] * aj_w;
    }
    __syncthreads();                   // everyone done reading Xs
    Xs[(r * 4 + hd) * 2 + half] = si;
    Xs[256 + (r * 4 + hd) * 2 + half] = sj;
    __syncthreads();
    if (t < 128) {
        int rr = t & 31, hh = t >> 5;
        int rown = row0 + rr;
        if (rown < N) {
            adi[rown * 4 + hh] = Xs[(rr * 4 + hh) * 2 + 0] + Xs[(rr * 4 + hh) * 2 + 1];
            adj[rown * 4 + hh] = Xs[256 + (rr * 4 + hh) * 2 + 0] + Xs[256 + (rr * 4 + hh) * 2 + 1];
        }
    }
}

// ---------------------------------------------------------------------------
// CSR build: zero -> histogram -> hierarchical scan -> scatter
// ---------------------------------------------------------------------------
__global__ __launch_bounds__(256) void k_zero(int* __restrict__ cnt, int N) {
    int tid = blockIdx.x * blockDim.x + threadIdx.x;
    if (tid < N) cnt[tid] = 0;
}

__global__ __launch_bounds__(256) void k_hist(const int* __restrict__ ei,
                                              int* __restrict__ cnt, int E) {
    int e = blockIdx.x * blockDim.x + threadIdx.x;
    if (e >= E) return;
    atomicAdd(&cnt[ei[E + e]], 1);
}

// level 1: per-block sums of 256-element chunks
__global__ __launch_bounds__(256) void k_partial(const int* __restrict__ cnt,
                                                 int* __restrict__ bsum, int N) {
    __shared__ int s[256];
    int t = threadIdx.x;
    int i = blockIdx.x * 256 + t;
    s[t] = (i < N) ? cnt[i] : 0;
    __syncthreads();
    for (int off = 128; off > 0; off >>= 1) {
        if (t < off) s[t] += s[t + off];
        __syncthreads();
    }
    if (t == 0) bsum[blockIdx.x] = s[0];
}

// level 2: single small block scans the block sums (NB <= 256*chunk)
__global__ __launch_bounds__(256) void k_scanblock(const int* __restrict__ bsum,
                                                   int* __restrict__ boff, int NB) {
    __shared__ int s[256];
    int t = threadIdx.x;
    int chunk = (NB + 255) >> 8;
    int b = t * chunk, e = min(b + chunk, NB);
    int sum = 0;
    for (int i = b; i < e; ++i) sum += bsum[i];
    s[t] = sum;
    __syncthreads();
    for (int off = 1; off < 256; off <<= 1) {
        int v = (t >= off) ? s[t - off] : 0;
        __syncthreads();
        s[t] += v;
        __syncthreads();
    }
    int run = (t == 0) ? 0 : s[t - 1];
    for (int i = b; i < e; ++i) { boff[i] = run; run += bsum[i]; }
}

// level 3: local exclusive scan + block offset -> rowoff, cursor
__global__ __launch_bounds__(256) void k_apply(const int* __restrict__ cnt,
                                               const int* __restrict__ boff,
                                               int* __restrict__ rowoff,
                                               int* __restrict__ cursor, int N) {
    __shared__ int s[256];
    int t = threadIdx.x;
    int i = blockIdx.x * 256 + t;
    int v = (i < N) ? cnt[i] : 0;
    s[t] = v;
    __syncthreads();
    for (int off = 1; off < 256; off <<= 1) {
        int x = (t >= off) ? s[t - off] : 0;
        __syncthreads();
        s[t] += x;
        __syncthreads();
    }
    int excl = s[t] - v + boff[blockIdx.x];
    if (i < N) { rowoff[i] = excl; cursor[i] = excl; }
    if (i == N - 1) rowoff[N] = excl + v;
}

__global__ __launch_bounds__(256) void k_scatter(const int* __restrict__ ei,
                                                 int* __restrict__ cursor,
                                                 int* __restrict__ csr_src, int E) {
    int e = blockIdx.x * blockDim.x + threadIdx.x;
    if (e >= E) return;
    int dst = ei[E + e];
    int pos = atomicAdd(&cursor[dst], 1);
    csr_src[pos] = ei[e];
}

// ---------------------------------------------------------------------------
// K3: one wave per node. Shuffle segment-max, register-accumulated
// numerator + denom, single write with bias. Zero atomics.
// ---------------------------------------------------------------------------
__global__ __launch_bounds__(256) void k_node(const int* __restrict__ rowoff,
                                              const int* __restrict__ csr_src,
                                              const float* __restrict__ h,
                                              const float* __restrict__ adi,
                                              const float* __restrict__ adj,
                                              const float* __restrict__ bias,
                                              float* __restrict__ out, int N) {
    int node = (blockIdx.x * blockDim.x + threadIdx.x) >> 6;
    if (node >= N) return;
    const int lane = threadIdx.x & 63;
    const int head = lane >> 4;

    const int beg = rowoff[node];
    const int end = rowoff[node + 1];

    // ---- pass A: per-head max of adj over neighbors ----
    float m = -1e30f;
    for (int i = beg + (lane >> 2); i < end; i += 16)
        m = fmaxf(m, adj[csr_src[i] * 4 + (lane & 3)]);
    #pragma unroll
    for (int mask = 4; mask <= 32; mask <<= 1)
        m = fmaxf(m, __shfl_xor(m, mask));
    float sm = __shfl(m, head);

    float ai = adi[node * 4 + head];
    float smax_l = lrelu(ai + sm);

    // ---- pass B: numerator (2 floats/lane) + denom ----
    float acc0 = 0.f, acc1 = 0.f, dsum = 0.f;
    for (int i = beg; i < end; ++i) {
        int src = csr_src[i];
        float aj = adj[src * 4 + head];
        float ex = __expf(lrelu(ai + aj) - smax_l);
        dsum += ex;
        float2 hv = ((const float2*)h)[(size_t)src * 64 + lane];
        acc0 += hv.x * ex;
        acc1 += hv.y * ex;
    }
    float inv = 1.f / (dsum + 1e-16f);
    float2 bv = ((const float2*)bias)[lane];
    float2 ov = make_float2(acc0 * inv + bv.x, acc1 * inv + bv.y);
    ((float2*)out)[(size_t)node * 64 + lane] = ov;
}

extern "C" void kernel_launch(void* const* d_in, const int* in_sizes, int n_in,
                              void* d_out, int out_size, void* d_ws, size_t ws_size,
                              hipStream_t stream) {
    const float* x    = (const float*)d_in[0];
    const int*   ei   = (const int*)d_in[1];
    const float* w    = (const float*)d_in[2];
    const float* att  = (const float*)d_in[3];
    const float* bias = (const float*)d_in[4];

    const int N = in_sizes[0] / 128;   // 50000
    const int E = in_sizes[1] / 2;     // 800000

    float* out = (float*)d_out;
    char*  wsb = (char*)d_ws;

    float* h   = (float*)wsb;                                  // N*128 f
    float* adi = h + (size_t)N * 128;                          // N*4 f
    float* adj = adi + (size_t)N * 4;                          // N*4 f
    int* cnt     = (int*)(adj + (size_t)N * 4);                // N
    int* rowoff  = cnt + N;                                    // N+1
    int* cursor  = rowoff + (N + 1);                           // N
    int* csr_src = cursor + N;                                 // E
    int* bsum    = csr_src + E;                                // NB
    int* boff    = bsum + 4096;                                // NB

    const int NB = (N + 255) / 256;

    k_gemm<<<(N + 31) / 32, 256, 0, stream>>>(x, w, att, h, adi, adj, N);

    k_zero<<<(N + 255) / 256, 256, 0, stream>>>(cnt, N);
    k_hist<<<(E + 255) / 256, 256, 0, stream>>>(ei, cnt, E);
    k_partial<<<NB, 256, 0, stream>>>(cnt, bsum, N);
    k_scanblock<<<1, 256, 0, stream>>>(bsum, boff, NB);
    k_apply<<<NB, 256, 0, stream>>>(cnt, boff, rowoff, cursor, N);
    k_scatter<<<(E + 255) / 256, 256, 0, stream>>>(ei, cursor, csr_src, E);

    {
        long long total = (long long)N * 64;
        int blocks = (int)((total + 255) / 256);
        k_node<<<blocks, 256, 0, stream>>>(rowoff, csr_src, h, adi, adj, bias, out, N);
    }
}